// Round 6
// baseline (30.730 us; speedup 1.0000x reference)
//
#include <hip/hip_runtime.h>

constexpr int N_NODES   = 50000;
constexpr int N_EDGES   = 800000;
constexpr int D_FEAT    = 96;
constexpr int DIM_H     = 128;
constexpr int N_CLASSES = 10;

constexpr int SHIFT  = 7;                                 // 128 nodes / bucket
constexpr int BNODES = 1 << SHIFT;
constexpr int NB     = (N_NODES + BNODES - 1) >> SHIFT;   // 391 buckets
constexpr int NBLK1  = 256;                               // phase-1 blocks
constexpr int EPB    = N_EDGES / NBLK1;                   // 3125 edges/block
constexpr int PREFW  = NB + 1;                            // 392
constexpr int EPT    = (EPB + 1023) / 1024;               // 4 edges/thread

static_assert(N_NODES <= (1 << 16), "16-bit id packing requires N_NODES <= 65536");
static_assert(N_EDGES % NBLK1 == 0, "exact edge split");
static_assert(D_FEAT % 8 == 0, "8-lane row dot needs D_FEAT % 8 == 0");

__device__ inline int wave_iscan(int v, int lane) {
#pragma unroll
    for (int off = 1; off < 64; off <<= 1) {
        int n = __shfl_up(v, off);
        if (lane >= off) v += n;
    }
    return v;
}

__device__ inline float wave_rsum(float v) {
#pragma unroll
    for (int off = 32; off > 0; off >>= 1) v += __shfl_down(v, off);
    return v;
}

// ---------------------------------------------------------------------------
// K1 (256 blocks x 1024 thr), single-pass:
//   1. issue this block's 3125 edges into REGISTERS (one global read of src+dst)
//   2. node dot y = x.a1 runs while edge loads are in flight
//   3. histogram + scan + LDS scatter straight from registers
//   4. coalesced linear write-out of binned (src<<16|dst) pairs
// ---------------------------------------------------------------------------
__global__ __launch_bounds__(1024) void k_prep(
    const float* __restrict__ x, const float* __restrict__ a1,
    const int* __restrict__ src, const int* __restrict__ dst,
    float* __restrict__ y, unsigned* __restrict__ pairs,
    int* __restrict__ prefg, int* __restrict__ ticket)
{
    __shared__ unsigned stage[EPB];            // 12.5 KB binned pairs
    __shared__ int hist[NB], run[NB], excl[PREFW];
    __shared__ int wsum[16];
    const int tid  = threadIdx.x;
    const int lane = tid & 63, wid = tid >> 6;
    const int blk  = blockIdx.x;

    if (blk == 0 && tid == 0)
        __hip_atomic_store(ticket, 0, __ATOMIC_RELAXED, __HIP_MEMORY_SCOPE_AGENT);

    // zero histogram first (LDS only, no global traffic)
    for (int t = tid; t < NB; t += 1024) hist[t] = 0;

    // ---- issue edge loads into registers (fully unrolled -> stays in VGPRs) ----
    const int e0 = blk * EPB;
    int sj[EPT], dj[EPT];
#pragma unroll
    for (int k = 0; k < EPT; ++k) {
        int j = tid + k * 1024;
        bool ok = j < EPB;
        sj[k] = ok ? src[e0 + j] : 0;
        dj[k] = ok ? dst[e0 + j] : (NB << SHIFT) - 1;  // dummy -> last bucket, filtered below
    }

    // ---- node dot overlaps the edge loads: 8 lanes/row, 3 x float4/lane ----
    {
        const float4* av = reinterpret_cast<const float4*>(a1);
        const int sub = tid & 7;
        const float4 a0  = av[sub * 3 + 0];
        const float4 a1v = av[sub * 3 + 1];
        const float4 a2v = av[sub * 3 + 2];
        const int g0 = (blk * 1024 + tid) >> 3;
        for (int r = g0; r < N_NODES; r += (NBLK1 * 1024) / 8) {
            const float4* row =
                reinterpret_cast<const float4*>(x + (size_t)r * D_FEAT) + sub * 3;
            float4 v0 = row[0], v1 = row[1], v2 = row[2];
            float s = v0.x * a0.x + v0.y * a0.y + v0.z * a0.z + v0.w * a0.w
                    + v1.x * a1v.x + v1.y * a1v.y + v1.z * a1v.z + v1.w * a1v.w
                    + v2.x * a2v.x + v2.y * a2v.y + v2.z * a2v.z + v2.w * a2v.w;
            s += __shfl_xor(s, 1);
            s += __shfl_xor(s, 2);
            s += __shfl_xor(s, 4);
            if (sub == 0) y[r] = s;
        }
    }
    __syncthreads();   // hist zero visible; edge loads long since landed

    // ---- histogram from registers ----
#pragma unroll
    for (int k = 0; k < EPT; ++k) {
        int j = tid + k * 1024;
        if (j < EPB) atomicAdd(&hist[((unsigned)dj[k]) >> SHIFT], 1);
    }
    __syncthreads();

    // ---- exclusive scan over NB bucket counts ----
    int v   = (tid < NB) ? hist[tid] : 0;
    int inc = wave_iscan(v, lane);
    if (lane == 63) wsum[wid] = inc;
    __syncthreads();
    int woff = 0;
#pragma unroll
    for (int w = 0; w < 16; ++w) if (w < wid) woff += wsum[w];
    if (tid < NB) { int e = inc - v + woff; excl[tid] = e; run[tid] = e; }
    if (tid == 0) {
        int t = 0;
#pragma unroll
        for (int w = 0; w < 16; ++w) t += wsum[w];
        excl[NB] = t;
    }
    __syncthreads();
    if (tid < PREFW) prefg[blk * PREFW + tid] = excl[tid];

    // ---- scatter from registers into binned LDS positions ----
#pragma unroll
    for (int k = 0; k < EPT; ++k) {
        int j = tid + k * 1024;
        if (j < EPB) {
            int pos = atomicAdd(&run[((unsigned)dj[k]) >> SHIFT], 1);
            stage[pos] = ((unsigned)sj[k] << 16) | (unsigned)dj[k];
        }
    }
    __syncthreads();

    // ---- coalesced linear write-out ----
    for (int j = tid; j < EPB; j += 1024)
        pairs[(size_t)blk * EPB + j] = stage[j];
}

// ---------------------------------------------------------------------------
// K2 (391 blocks x 512 thr): bucket accumulation in LDS. Two threads walk
// each producer segment. Relu-split partials; ticketed last block computes
// the final rank-1 output in-kernel.
// ---------------------------------------------------------------------------
__global__ __launch_bounds__(512) void k_accum_final(
    const unsigned* __restrict__ pairs, const int* __restrict__ prefg,
    const float* __restrict__ y, const float* __restrict__ b1,
    const float* __restrict__ a2, const float* __restrict__ b2,
    float* __restrict__ PMpart, int* __restrict__ ticket,
    float* __restrict__ out)
{
    __shared__ float acc[BNODES];
    __shared__ int   soff[NBLK1], scnt[NBLK1];
    __shared__ float redp[8], redm[8], redcp[8], redcn[8];
    __shared__ int   islast;
    __shared__ float tval;
    const int b    = blockIdx.x;
    const int tid  = threadIdx.x;
    const int lane = tid & 63, wid = tid >> 6;

    if (tid < BNODES) acc[tid] = 0.f;
    if (tid < NBLK1) {
        int st = prefg[tid * PREFW + b];
        soff[tid] = st;
        scnt[tid] = prefg[tid * PREFW + b + 1] - st;
    }
    __syncthreads();

    // 512 threads -> 2 per segment
    {
        const int seg = tid >> 1, h = tid & 1;
        const int n = scnt[seg];
        const unsigned* p0 = pairs + (size_t)seg * EPB + soff[seg];
        for (int j = h; j < n; j += 2) {
            unsigned p = p0[j];
            atomicAdd(&acc[p & (BNODES - 1)], y[p >> 16]);
        }
    }
    __syncthreads();

    // relu-split partials for this bucket
    float pp = 0.f, mm = 0.f;
    if (tid < BNODES) {
        int g = (b << SHIFT) + tid;
        if (g < N_NODES) {
            float v = acc[tid];
            pp = fmaxf(v, 0.f);
            mm = fminf(v, 0.f);
        }
    }
    pp = wave_rsum(pp);
    mm = wave_rsum(mm);
    if (lane == 0) { redp[wid] = pp; redm[wid] = mm; }
    __syncthreads();
    if (tid == 0) {
        float tp = 0.f, tm = 0.f;
#pragma unroll
        for (int w = 0; w < 8; ++w) { tp += redp[w]; tm += redm[w]; }
        __hip_atomic_store(&PMpart[2 * b],     tp, __ATOMIC_RELAXED, __HIP_MEMORY_SCOPE_AGENT);
        __hip_atomic_store(&PMpart[2 * b + 1], tm, __ATOMIC_RELAXED, __HIP_MEMORY_SCOPE_AGENT);
        int t = __hip_atomic_fetch_add(ticket, 1, __ATOMIC_ACQ_REL, __HIP_MEMORY_SCOPE_AGENT);
        islast = (t == NB - 1);
    }
    __syncthreads();

    if (islast) {
        float P = 0.f, M = 0.f, cp = 0.f, cn = 0.f;
        if (tid < NB) {
            P = __hip_atomic_load(&PMpart[2 * tid],     __ATOMIC_RELAXED, __HIP_MEMORY_SCOPE_AGENT);
            M = __hip_atomic_load(&PMpart[2 * tid + 1], __ATOMIC_RELAXED, __HIP_MEMORY_SCOPE_AGENT);
        }
        if (tid < DIM_H) {
            float bv = b1[tid], pr = a2[tid] * bv;
            cp = (bv > 0.f) ? pr : 0.f;
            cn = (bv < 0.f) ? pr : 0.f;
        }
        P  = wave_rsum(P);
        M  = wave_rsum(M);
        cp = wave_rsum(cp);
        cn = wave_rsum(cn);
        __syncthreads();
        if (lane == 0) { redp[wid] = P; redm[wid] = M; redcp[wid] = cp; redcn[wid] = cn; }
        __syncthreads();
        if (tid == 0) {
            float sP = 0.f, sM = 0.f, sCP = 0.f, sCN = 0.f;
#pragma unroll
            for (int w = 0; w < 8; ++w) {
                sP += redp[w]; sM += redm[w]; sCP += redcp[w]; sCN += redcn[w];
            }
            tval = sP * sCP + sM * sCN;
        }
        __syncthreads();
        if (tid < N_CLASSES) out[tid] = tval * b2[tid];
    }
}

// ---------------------------------------------------------------------------
// fallback path (ws too small): device-scope atomic scatter
// ---------------------------------------------------------------------------
__global__ void fb_node_dot(const float* __restrict__ x, const float* __restrict__ a1,
                            float* __restrict__ y) {
    int i = blockIdx.x * blockDim.x + threadIdx.x;
    if (i >= N_NODES) return;
    const float4* row = reinterpret_cast<const float4*>(x + (size_t)i * D_FEAT);
    const float4* av  = reinterpret_cast<const float4*>(a1);
    float acc = 0.f;
#pragma unroll
    for (int k = 0; k < D_FEAT / 4; ++k) {
        float4 v = row[k], a = av[k];
        acc += v.x * a.x + v.y * a.y + v.z * a.z + v.w * a.w;
    }
    y[i] = acc;
}

__global__ void fb_scatter(const int* __restrict__ src, const int* __restrict__ dst,
                           const float* __restrict__ y, float* __restrict__ s) {
    int e = blockIdx.x * blockDim.x + threadIdx.x;
    if (e >= N_EDGES) return;
    atomicAdd(&s[dst[e]], y[src[e]]);
}

__global__ void fb_reduce(const float* __restrict__ s, float* __restrict__ PM) {
    float p = 0.f, m = 0.f;
    for (int i = blockIdx.x * blockDim.x + threadIdx.x; i < N_NODES;
         i += gridDim.x * blockDim.x) {
        float v = s[i];
        p += fmaxf(v, 0.f);
        m += fminf(v, 0.f);
    }
    p = wave_rsum(p);
    m = wave_rsum(m);
    __shared__ float lp[4], lm[4];
    int wid = threadIdx.x >> 6, lane = threadIdx.x & 63;
    if (lane == 0) { lp[wid] = p; lm[wid] = m; }
    __syncthreads();
    if (threadIdx.x == 0) {
        float tp = 0.f, tm = 0.f;
        for (int w = 0; w < (int)(blockDim.x >> 6); ++w) { tp += lp[w]; tm += lm[w]; }
        atomicAdd(&PM[0], tp);
        atomicAdd(&PM[1], tm);
    }
}

__global__ void fb_final(const float* __restrict__ b1, const float* __restrict__ a2,
                         const float* __restrict__ b2, const float* __restrict__ PM,
                         float* __restrict__ out) {
    int t = threadIdx.x;
    float bv = b1[t], prod = a2[t] * bv;
    float cp = (bv > 0.f) ? prod : 0.f;
    float cn = (bv < 0.f) ? prod : 0.f;
    cp = wave_rsum(cp);
    cn = wave_rsum(cn);
    __shared__ float scp[2], scn[2], tv;
    if ((t & 63) == 0) { scp[t >> 6] = cp; scn[t >> 6] = cn; }
    __syncthreads();
    if (t == 0) tv = PM[0] * (scp[0] + scp[1]) + PM[1] * (scn[0] + scn[1]);
    __syncthreads();
    if (t < N_CLASSES) out[t] = tv * b2[t];
}

extern "C" void kernel_launch(void* const* d_in, const int* in_sizes, int n_in,
                              void* d_out, int out_size, void* d_ws, size_t ws_size,
                              hipStream_t stream) {
    const float* x  = (const float*)d_in[0];
    const int*   ei = (const int*)d_in[1];   // [src(800000), dst(800000)]
    const float* a1 = (const float*)d_in[2];
    const float* b1 = (const float*)d_in[3];
    const float* a2 = (const float*)d_in[4];
    const float* b2 = (const float*)d_in[5];
    float* out = (float*)d_out;

    // ws layout: pairs u32[N_EDGES] | y f32[N_NODES] | prefg i32[NBLK1*PREFW]
    //          | PMpart f32[2*NB] | ticket i32
    unsigned* pairs  = (unsigned*)d_ws;
    float*    y      = (float*)(pairs + N_EDGES);
    int*      prefg  = (int*)(y + N_NODES);
    float*    PMpart = (float*)(prefg + (size_t)NBLK1 * PREFW);
    int*      ticket = (int*)(PMpart + 2 * NB);

    size_t need = (size_t)N_EDGES * 4 + (size_t)N_NODES * 4 +
                  (size_t)NBLK1 * PREFW * 4 + (size_t)2 * NB * 4 + 4;

    if (ws_size >= need) {
        k_prep<<<NBLK1, 1024, 0, stream>>>(x, a1, ei, ei + N_EDGES, y, pairs, prefg, ticket);
        k_accum_final<<<NB, 512, 0, stream>>>(pairs, prefg, y, b1, a2, b2,
                                              PMpart, ticket, out);
    } else {
        float* yf = (float*)d_ws;
        float* s  = yf + N_NODES;
        float* PM = s + N_NODES;
        hipMemsetAsync(s, 0, (N_NODES + 2) * sizeof(float), stream);
        fb_node_dot<<<(N_NODES + 255) / 256, 256, 0, stream>>>(x, a1, yf);
        fb_scatter<<<(N_EDGES + 255) / 256, 256, 0, stream>>>(ei, ei + N_EDGES, yf, s);
        fb_reduce<<<196, 256, 0, stream>>>(s, PM);
        fb_final<<<1, DIM_H, 0, stream>>>(b1, a2, b2, PM, out);
    }
}

// Round 7
// 30.173 us; speedup vs baseline: 1.0185x; 1.0185x over previous
//
#include <hip/hip_runtime.h>

constexpr int N_NODES   = 50000;
constexpr int N_EDGES   = 800000;
constexpr int D_FEAT    = 96;
constexpr int DIM_H     = 128;
constexpr int N_CLASSES = 10;

constexpr int SHIFT  = 8;                                 // 256 nodes / bucket
constexpr int BNODES = 1 << SHIFT;
constexpr int NB     = (N_NODES + BNODES - 1) >> SHIFT;   // 196 buckets
constexpr int NBLK1  = 500;                               // phase-1 blocks (~2/CU)
constexpr int THR1   = 512;
constexpr int EPB    = N_EDGES / NBLK1;                   // 1600 edges/block
constexpr int PREFW  = NB + 1;                            // 197

static_assert(N_NODES <= (1 << 16), "16-bit id packing requires N_NODES <= 65536");
static_assert(N_EDGES % NBLK1 == 0, "exact edge split");
static_assert(D_FEAT % 8 == 0, "8-lane row dot needs D_FEAT % 8 == 0");

__device__ inline int wave_iscan(int v, int lane) {
#pragma unroll
    for (int off = 1; off < 64; off <<= 1) {
        int n = __shfl_up(v, off);
        if (lane >= off) v += n;
    }
    return v;
}

__device__ inline float wave_rsum(float v) {
#pragma unroll
    for (int off = 32; off > 0; off >>= 1) v += __shfl_down(v, off);
    return v;
}

// ---------------------------------------------------------------------------
// K1 (500 blocks x 512 thr, ~2 blocks/CU so barrier phases overlap across
// blocks): (a) y = x.a1 with 8 lanes/row; (b) counting-sort this block's
// 1600 edges by dst>>8 into LDS, write out linearly (coalesced) + prefix
// table. Second src/dst read hits L1 (6.4 KB slice). No global atomics.
// ---------------------------------------------------------------------------
__global__ __launch_bounds__(THR1) void k_prep(
    const float* __restrict__ x, const float* __restrict__ a1,
    const int* __restrict__ src, const int* __restrict__ dst,
    float* __restrict__ y, unsigned* __restrict__ pairs,
    int* __restrict__ prefg, int* __restrict__ ticket)
{
    __shared__ unsigned stage[EPB];            // 6.4 KB binned pairs
    __shared__ int hist[NB], run[NB], excl[PREFW];
    __shared__ int wsum[THR1 / 64];
    const int tid  = threadIdx.x;
    const int lane = tid & 63, wid = tid >> 6;
    const int blk  = blockIdx.x;

    if (blk == 0 && tid == 0)
        __hip_atomic_store(ticket, 0, __ATOMIC_RELAXED, __HIP_MEMORY_SCOPE_AGENT);

    for (int t = tid; t < NB; t += THR1) hist[t] = 0;

    // ---- part A: node dot, 8 lanes/row, 3 x float4/lane ----
    {
        const float4* av = reinterpret_cast<const float4*>(a1);
        const int sub = tid & 7;
        const float4 a0  = av[sub * 3 + 0];
        const float4 a1v = av[sub * 3 + 1];
        const float4 a2v = av[sub * 3 + 2];
        const int g0 = (blk * THR1 + tid) >> 3;
        for (int r = g0; r < N_NODES; r += (NBLK1 * THR1) / 8) {
            const float4* row =
                reinterpret_cast<const float4*>(x + (size_t)r * D_FEAT) + sub * 3;
            float4 v0 = row[0], v1 = row[1], v2 = row[2];
            float s = v0.x * a0.x + v0.y * a0.y + v0.z * a0.z + v0.w * a0.w
                    + v1.x * a1v.x + v1.y * a1v.y + v1.z * a1v.z + v1.w * a1v.w
                    + v2.x * a2v.x + v2.y * a2v.y + v2.z * a2v.z + v2.w * a2v.w;
            s += __shfl_xor(s, 1);
            s += __shfl_xor(s, 2);
            s += __shfl_xor(s, 4);
            if (sub == 0) y[r] = s;
        }
    }
    __syncthreads();

    // ---- histogram of dst buckets ----
    const int e0 = blk * EPB;
    for (int j = tid; j < EPB; j += THR1)
        atomicAdd(&hist[((unsigned)dst[e0 + j]) >> SHIFT], 1);
    __syncthreads();

    // ---- exclusive scan over NB bucket counts ----
    int v   = (tid < NB) ? hist[tid] : 0;
    int inc = wave_iscan(v, lane);
    if (lane == 63) wsum[wid] = inc;
    __syncthreads();
    int woff = 0;
#pragma unroll
    for (int w = 0; w < THR1 / 64; ++w) if (w < wid) woff += wsum[w];
    if (tid < NB) { int e = inc - v + woff; excl[tid] = e; run[tid] = e; }
    if (tid == 0) {
        int t = 0;
#pragma unroll
        for (int w = 0; w < THR1 / 64; ++w) t += wsum[w];
        excl[NB] = t;
    }
    __syncthreads();
    if (tid < PREFW) prefg[blk * PREFW + tid] = excl[tid];

    // ---- scatter into binned LDS positions (src/dst re-read: L1-warm) ----
    for (int j = tid; j < EPB; j += THR1) {
        int d = dst[e0 + j];
        int s = src[e0 + j];
        int pos = atomicAdd(&run[((unsigned)d) >> SHIFT], 1);
        stage[pos] = ((unsigned)s << 16) | (unsigned)d;
    }
    __syncthreads();

    // ---- coalesced linear write-out ----
    for (int j = tid; j < EPB; j += THR1)
        pairs[(size_t)blk * EPB + j] = stage[j];
}

// ---------------------------------------------------------------------------
// K2 (196 blocks x 1024 thr = 16 waves/CU for gather-latency hiding):
// bucket accumulation in LDS, 2 threads per producer segment (500 segs).
// Relu-split partials; ticketed last block computes final output in-kernel.
// ---------------------------------------------------------------------------
__global__ __launch_bounds__(1024) void k_accum_final(
    const unsigned* __restrict__ pairs, const int* __restrict__ prefg,
    const float* __restrict__ y, const float* __restrict__ b1,
    const float* __restrict__ a2, const float* __restrict__ b2,
    float* __restrict__ PMpart, int* __restrict__ ticket,
    float* __restrict__ out)
{
    __shared__ float acc[BNODES];
    __shared__ int   soff[NBLK1], scnt[NBLK1];
    __shared__ float redp[16], redm[16], redcp[16], redcn[16];
    __shared__ int   islast;
    __shared__ float tval;
    const int b    = blockIdx.x;
    const int tid  = threadIdx.x;
    const int lane = tid & 63, wid = tid >> 6;

    if (tid < BNODES) acc[tid] = 0.f;
    for (int t = tid; t < NBLK1; t += 1024) {
        int st = prefg[t * PREFW + b];
        soff[t] = st;
        scnt[t] = prefg[t * PREFW + b + 1] - st;
    }
    __syncthreads();

    // 1024 threads -> 2 per segment (seg = tid>>1, half = tid&1); 500 segs
    {
        const int seg = tid >> 1, h = tid & 1;
        if (seg < NBLK1) {
            const int n = scnt[seg];
            const unsigned* p0 = pairs + (size_t)seg * EPB + soff[seg];
            for (int j = h; j < n; j += 2) {
                unsigned p = p0[j];
                atomicAdd(&acc[p & (BNODES - 1)], y[p >> 16]);
            }
        }
    }
    __syncthreads();

    // relu-split partials for this bucket
    float pp = 0.f, mm = 0.f;
    if (tid < BNODES) {
        int g = (b << SHIFT) + tid;
        if (g < N_NODES) {
            float v = acc[tid];
            pp = fmaxf(v, 0.f);
            mm = fminf(v, 0.f);
        }
    }
    pp = wave_rsum(pp);
    mm = wave_rsum(mm);
    if (lane == 0) { redp[wid] = pp; redm[wid] = mm; }
    __syncthreads();
    if (tid == 0) {
        float tp = 0.f, tm = 0.f;
#pragma unroll
        for (int w = 0; w < 16; ++w) { tp += redp[w]; tm += redm[w]; }
        __hip_atomic_store(&PMpart[2 * b],     tp, __ATOMIC_RELAXED, __HIP_MEMORY_SCOPE_AGENT);
        __hip_atomic_store(&PMpart[2 * b + 1], tm, __ATOMIC_RELAXED, __HIP_MEMORY_SCOPE_AGENT);
        int t = __hip_atomic_fetch_add(ticket, 1, __ATOMIC_ACQ_REL, __HIP_MEMORY_SCOPE_AGENT);
        islast = (t == NB - 1);
    }
    __syncthreads();

    if (islast) {
        float P = 0.f, M = 0.f, cp = 0.f, cn = 0.f;
        if (tid < NB) {
            P = __hip_atomic_load(&PMpart[2 * tid],     __ATOMIC_RELAXED, __HIP_MEMORY_SCOPE_AGENT);
            M = __hip_atomic_load(&PMpart[2 * tid + 1], __ATOMIC_RELAXED, __HIP_MEMORY_SCOPE_AGENT);
        }
        if (tid < DIM_H) {
            float bv = b1[tid], pr = a2[tid] * bv;
            cp = (bv > 0.f) ? pr : 0.f;
            cn = (bv < 0.f) ? pr : 0.f;
        }
        P  = wave_rsum(P);
        M  = wave_rsum(M);
        cp = wave_rsum(cp);
        cn = wave_rsum(cn);
        __syncthreads();
        if (lane == 0) { redp[wid] = P; redm[wid] = M; redcp[wid] = cp; redcn[wid] = cn; }
        __syncthreads();
        if (tid == 0) {
            float sP = 0.f, sM = 0.f, sCP = 0.f, sCN = 0.f;
#pragma unroll
            for (int w = 0; w < 16; ++w) {
                sP += redp[w]; sM += redm[w]; sCP += redcp[w]; sCN += redcn[w];
            }
            tval = sP * sCP + sM * sCN;
        }
        __syncthreads();
        if (tid < N_CLASSES) out[tid] = tval * b2[tid];
    }
}

// ---------------------------------------------------------------------------
// fallback path (ws too small): device-scope atomic scatter
// ---------------------------------------------------------------------------
__global__ void fb_node_dot(const float* __restrict__ x, const float* __restrict__ a1,
                            float* __restrict__ y) {
    int i = blockIdx.x * blockDim.x + threadIdx.x;
    if (i >= N_NODES) return;
    const float4* row = reinterpret_cast<const float4*>(x + (size_t)i * D_FEAT);
    const float4* av  = reinterpret_cast<const float4*>(a1);
    float acc = 0.f;
#pragma unroll
    for (int k = 0; k < D_FEAT / 4; ++k) {
        float4 v = row[k], a = av[k];
        acc += v.x * a.x + v.y * a.y + v.z * a.z + v.w * a.w;
    }
    y[i] = acc;
}

__global__ void fb_scatter(const int* __restrict__ src, const int* __restrict__ dst,
                           const float* __restrict__ y, float* __restrict__ s) {
    int e = blockIdx.x * blockDim.x + threadIdx.x;
    if (e >= N_EDGES) return;
    atomicAdd(&s[dst[e]], y[src[e]]);
}

__global__ void fb_reduce(const float* __restrict__ s, float* __restrict__ PM) {
    float p = 0.f, m = 0.f;
    for (int i = blockIdx.x * blockDim.x + threadIdx.x; i < N_NODES;
         i += gridDim.x * blockDim.x) {
        float v = s[i];
        p += fmaxf(v, 0.f);
        m += fminf(v, 0.f);
    }
    p = wave_rsum(p);
    m = wave_rsum(m);
    __shared__ float lp[4], lm[4];
    int wid = threadIdx.x >> 6, lane = threadIdx.x & 63;
    if (lane == 0) { lp[wid] = p; lm[wid] = m; }
    __syncthreads();
    if (threadIdx.x == 0) {
        float tp = 0.f, tm = 0.f;
        for (int w = 0; w < (int)(blockDim.x >> 6); ++w) { tp += lp[w]; tm += lm[w]; }
        atomicAdd(&PM[0], tp);
        atomicAdd(&PM[1], tm);
    }
}

__global__ void fb_final(const float* __restrict__ b1, const float* __restrict__ a2,
                         const float* __restrict__ b2, const float* __restrict__ PM,
                         float* __restrict__ out) {
    int t = threadIdx.x;
    float bv = b1[t], prod = a2[t] * bv;
    float cp = (bv > 0.f) ? prod : 0.f;
    float cn = (bv < 0.f) ? prod : 0.f;
    cp = wave_rsum(cp);
    cn = wave_rsum(cn);
    __shared__ float scp[2], scn[2], tv;
    if ((t & 63) == 0) { scp[t >> 6] = cp; scn[t >> 6] = cn; }
    __syncthreads();
    if (t == 0) tv = PM[0] * (scp[0] + scp[1]) + PM[1] * (scn[0] + scn[1]);
    __syncthreads();
    if (t < N_CLASSES) out[t] = tv * b2[t];
}

extern "C" void kernel_launch(void* const* d_in, const int* in_sizes, int n_in,
                              void* d_out, int out_size, void* d_ws, size_t ws_size,
                              hipStream_t stream) {
    const float* x  = (const float*)d_in[0];
    const int*   ei = (const int*)d_in[1];   // [src(800000), dst(800000)]
    const float* a1 = (const float*)d_in[2];
    const float* b1 = (const float*)d_in[3];
    const float* a2 = (const float*)d_in[4];
    const float* b2 = (const float*)d_in[5];
    float* out = (float*)d_out;

    // ws layout: pairs u32[N_EDGES] | y f32[N_NODES] | prefg i32[NBLK1*PREFW]
    //          | PMpart f32[2*NB] | ticket i32
    unsigned* pairs  = (unsigned*)d_ws;
    float*    y      = (float*)(pairs + N_EDGES);
    int*      prefg  = (int*)(y + N_NODES);
    float*    PMpart = (float*)(prefg + (size_t)NBLK1 * PREFW);
    int*      ticket = (int*)(PMpart + 2 * NB);

    size_t need = (size_t)N_EDGES * 4 + (size_t)N_NODES * 4 +
                  (size_t)NBLK1 * PREFW * 4 + (size_t)2 * NB * 4 + 4;

    if (ws_size >= need) {
        k_prep<<<NBLK1, THR1, 0, stream>>>(x, a1, ei, ei + N_EDGES, y, pairs, prefg, ticket);
        k_accum_final<<<NB, 1024, 0, stream>>>(pairs, prefg, y, b1, a2, b2,
                                               PMpart, ticket, out);
    } else {
        float* yf = (float*)d_ws;
        float* s  = yf + N_NODES;
        float* PM = s + N_NODES;
        hipMemsetAsync(s, 0, (N_NODES + 2) * sizeof(float), stream);
        fb_node_dot<<<(N_NODES + 255) / 256, 256, 0, stream>>>(x, a1, yf);
        fb_scatter<<<(N_EDGES + 255) / 256, 256, 0, stream>>>(ei, ei + N_EDGES, yf, s);
        fb_reduce<<<196, 256, 0, stream>>>(s, PM);
        fb_final<<<1, DIM_H, 0, stream>>>(b1, a2, b2, PM, out);
    }
}